// Round 7
// baseline (253.261 us; speedup 1.0000x reference)
//
#include <hip/hip_runtime.h>
#include <hip/hip_bf16.h>
#include <hip/hip_fp8.h>

#define N_NODES 50000
#define N_EDGES 1600000
#define N_GRAPHS 64
#define D_IN 128
#define D_H 512
#define D_OUT 16

// atomic-free CSR build: buckets of 128 rows, 391 blocks for both phases
#define NBUK 391                      // ceil(50000/128)
#define BUK_CAP 4608                  // mean 4092 + ~8 sigma
#define P1_EDGES 4096                 // edges per partition block
#define P1_BLOCKS ((N_EDGES + P1_EDGES - 1) / P1_EDGES)   // 391

#define MSPLIT 8                      // M-tile interleave factor for the GEMM

// feature-half stride in u16 units: [2][(N_NODES+1) * 32] per hop buffer
#define HSTRIDE ((size_t)(N_NODES + 1) * 32)

typedef short bf16x8 __attribute__((ext_vector_type(8)));
typedef float f32x4 __attribute__((ext_vector_type(4)));
typedef float f32x2 __attribute__((ext_vector_type(2)));

static __device__ __forceinline__ unsigned short f2bf(float f) {
    __hip_bfloat16 h = __float2bfloat16(f);   // RNE
    return *(unsigned short*)&h;
}

static __device__ __forceinline__ float2 fp8x2_dec(unsigned short u) {
    __hip_fp8x2_e4m3 p;
    p.__x = (__hip_fp8x2_storage_t)u;
    return static_cast<float2>(p);
}

static __device__ __forceinline__ unsigned short fp8x2_enc(float a, float b) {
    __hip_fp8_e4m3 pa(a), pb(b);
    return (unsigned short)((unsigned)pa.__x | ((unsigned)pb.__x << 8));
}

// decode 8 fp8 (one uint2 = 8B slice) and accumulate into 4 packed f32x2
static __device__ __forceinline__ void dec8_add(uint2 u, f32x2* acc) {
    unsigned vv[2] = {u.x, u.y};
#pragma unroll
    for (int w = 0; w < 2; ++w) {
        float2 a = fp8x2_dec((unsigned short)(vv[w] & 0xFFFFu));
        float2 b = fp8x2_dec((unsigned short)(vv[w] >> 16));
        f32x2 av; av.x = a.x; av.y = a.y;
        f32x2 bv; bv.x = b.x; bv.y = b.y;
        acc[w * 2 + 0] += av;
        acc[w * 2 + 1] += bv;
    }
}

// ---------------------------------------------------------------- CSR build (atomic-free)
// P1: 391 blocks x 512 threads, 4096 edges each. rec = (buk:9)<<23 | (rlow:7)<<16 | col:16.

__global__ __launch_bounds__(512) void partition_edges(const int* __restrict__ row,
                                                       const int* __restrict__ col,
                                                       int* __restrict__ bucket_cnt,
                                                       unsigned* __restrict__ edge_buf) {
    __shared__ unsigned recs[P1_EDGES];     // 16 KB
    __shared__ unsigned sorted[P1_EDGES];   // 16 KB
    __shared__ int hist4[4][NBUK];          // per-wave-pair counts -> local bases
    __shared__ int cur4[4][NBUK];
    __shared__ int gbase[NBUK];
    __shared__ int scan[512];
    int tid = threadIdx.x;
    int w2 = tid >> 7;                      // wave-pair 0..3
    int e0 = blockIdx.x * P1_EDGES;
    int m = N_EDGES - e0; if (m > P1_EDGES) m = P1_EDGES;

    for (int i = tid; i < 4 * NBUK; i += 512) ((int*)hist4)[i] = 0;
    for (int i = tid; i < 4 * NBUK; i += 512) ((int*)cur4)[i] = 0;
    __syncthreads();
    for (int i = tid; i < m; i += 512) {
        int r = row[e0 + i];
        int c = col[e0 + i];
        int buk = r >> 7;
        recs[i] = ((unsigned)buk << 23) | ((unsigned)(r & 127) << 16) | (unsigned)c;
        atomicAdd(&hist4[w2][buk], 1);
    }
    __syncthreads();
    int tot = 0;
    if (tid < NBUK) tot = hist4[0][tid] + hist4[1][tid] + hist4[2][tid] + hist4[3][tid];
    scan[tid] = (tid < NBUK) ? tot : 0;
    __syncthreads();
    for (int off = 1; off < 512; off <<= 1) {
        int v = (tid >= off) ? scan[tid - off] : 0;
        __syncthreads();
        scan[tid] += v;
        __syncthreads();
    }
    if (tid < NBUK) {
        int run = (tid == 0) ? 0 : scan[tid - 1];   // block-local excl base
        gbase[tid] = (tot > 0) ? atomicAdd(&bucket_cnt[tid], tot) : 0;  // reserve range
#pragma unroll
        for (int w = 0; w < 4; ++w) {               // per-sub-group local bases
            int c = hist4[w][tid];
            hist4[w][tid] = run;
            run += c;
        }
    }
    __syncthreads();
    for (int i = tid; i < m; i += 512) {            // rank + reorder (bucket-major)
        unsigned rec = recs[i];
        int buk = rec >> 23;
        int rank = atomicAdd(&cur4[w2][buk], 1);
        sorted[hist4[w2][buk] + rank] = rec;
    }
    __syncthreads();
    for (int p = tid; p < m; p += 512) {            // coalesced-run writes
        unsigned rec = sorted[p];
        int buk = rec >> 23;
        edge_buf[(size_t)buk * BUK_CAP + gbase[buk] + (p - hist4[0][buk])] = rec;
    }
}

// P2: one block per bucket (391 x 512); inline scan of bucket_cnt; LDS-cursor scatter.
__global__ __launch_bounds__(512) void finalize_csr(const unsigned* __restrict__ edge_buf,
                                                    const int* __restrict__ bucket_cnt,
                                                    int* __restrict__ rowptr,
                                                    float* __restrict__ invdeg,
                                                    unsigned short* __restrict__ csr_col) {
    __shared__ int hist[128], excl[128], cur[128];
    __shared__ int scan[512];
    int b = blockIdx.x;
    int tid = threadIdx.x;
    scan[tid] = (tid < NBUK) ? bucket_cnt[tid] : 0;
    __syncthreads();
    for (int off = 1; off < 512; off <<= 1) {
        int v = (tid >= off) ? scan[tid - off] : 0;
        __syncthreads();
        scan[tid] += v;
        __syncthreads();
    }
    int cnt = bucket_cnt[b];
    int base = (b == 0) ? 0 : scan[b - 1];
    const unsigned* src = edge_buf + (size_t)b * BUK_CAP;
    __syncthreads();
    if (tid < 128) { hist[tid] = 0; cur[tid] = 0; }
    __syncthreads();
    for (int i = tid; i < cnt; i += 512)
        atomicAdd(&hist[(src[i] >> 16) & 127], 1);
    __syncthreads();
    scan[tid] = (tid < 128) ? hist[tid] : 0;
    __syncthreads();
    for (int off = 1; off < 512; off <<= 1) {
        int v = (tid >= off) ? scan[tid - off] : 0;
        __syncthreads();
        scan[tid] += v;
        __syncthreads();
    }
    if (tid < 128) excl[tid] = (tid == 0) ? 0 : scan[tid - 1];
    __syncthreads();
    int r = b * 128 + tid;
    if (tid < 128 && r < N_NODES) {
        rowptr[r] = base + excl[tid];
        invdeg[r] = 1.0f / (float)(hist[tid] + 1);   // +1: self loop
    }
    if (b == NBUK - 1 && tid == 0) rowptr[N_NODES] = base + cnt;
    for (int i = tid; i < cnt; i += 512) {
        unsigned rec = src[i];
        int rl = (rec >> 16) & 127;
        int pos = excl[rl] + atomicAdd(&cur[rl], 1);
        csr_col[base + pos] = (unsigned short)(rec & 0xFFFFu);
    }
}

// ---------------------------------------------------------------- merged prep
// [0,12500): convert_x (feature-half-major); [12500,12756): make_w1p;
// [12756,12790): fold_w + graph bounds + zero-row sentinels (2 halves x 3 bufs).

__global__ __launch_bounds__(256) void prep(const float* __restrict__ x,
                                            unsigned short* __restrict__ xf,
                                            const float* __restrict__ w1,
                                            unsigned short* __restrict__ w1p,
                                            const float* __restrict__ w2,
                                            const float* __restrict__ wc,
                                            const float* __restrict__ b2,
                                            const float* __restrict__ bc,
                                            const int* __restrict__ batch,
                                            float* __restrict__ wcomb,
                                            float* __restrict__ bcomb,
                                            int* __restrict__ gcnt,
                                            int* __restrict__ gstart,
                                            unsigned short* __restrict__ h0f,
                                            unsigned short* __restrict__ h1f) {
    int b = blockIdx.x;
    int tid = threadIdx.x;
    if (b < 12500) {                                // convert_x: 12500*256 == N*64 exactly
        int i = b * 256 + tid;
        float2 v = ((const float2*)x)[i];           // float2 idx i == (n, j=h*32+s)
        int n = i >> 6, j = i & 63;
        int h = j >> 5, s = j & 31;
        xf[(size_t)h * HSTRIDE + (size_t)n * 32 + s] = fp8x2_enc(v.x, v.y);
        return;
    }
    if (b < 12756) {                                // make_w1p: 256 blocks, 65536 elems
        int i = (b - 12500) * 256 + tid;
        int j = i & 7, lane = (i >> 3) & 63, s = (i >> 9) & 3, t = i >> 11;
        int k = s * 32 + (lane >> 4) * 8 + j;
        int n = t * 16 + (lane & 15);
        w1p[i] = f2bf(w1[(size_t)k * D_H + n]);
        return;
    }
    int fb = b - 12756;                             // fold_w blocks 0..33
    if (fb == 33) {
        if (tid < N_GRAPHS) {
            int g = tid;
            int lo = 0, hi = N_NODES;
            while (lo < hi) { int mid = (lo + hi) >> 1; if (batch[mid] < g) lo = mid + 1; else hi = mid; }
            int a = lo;
            lo = 0; hi = N_NODES;
            while (lo < hi) { int mid = (lo + hi) >> 1; if (batch[mid] < g + 1) lo = mid + 1; else hi = mid; }
            gcnt[g] = lo - a;
            gstart[g] = a;
            if (g == N_GRAPHS - 1) gstart[N_GRAPHS] = N_NODES;
        } else if (tid >= 64 && tid < 256) {        // zero sentinels: 6 x 32 u16
            int t = tid - 64;
            if (t < 192) {
                int which = t >> 5;                 // 0..5
                unsigned short* bp = (which < 2) ? xf : (which < 4 ? h0f : h1f);
                bp[(size_t)(which & 1) * HSTRIDE + (size_t)N_NODES * 32 + (t & 31)] = 0;
            }
        }
        return;
    }
    int o = tid & 15, kl = tid >> 4;
    int k = fb * 16 + kl;
    if (k > D_H) return;
    const float* wr = (k < D_H) ? (w2 + (size_t)k * D_H) : b2;
    float s = 0.f;
    for (int j = 0; j < D_H; j += 4) {
        s += wr[j + 0] * wc[(j + 0) * D_OUT + o]
           + wr[j + 1] * wc[(j + 1) * D_OUT + o]
           + wr[j + 2] * wc[(j + 2) * D_OUT + o]
           + wr[j + 3] * wc[(j + 3) * D_OUT + o];
    }
    if (k < D_H) wcomb[k * D_OUT + o] = s;
    else         bcomb[o] = s + bc[o];
}

// ---------------------------------------------------------------- propagation (fp8 storage, f32 accumulate)
// FEATURE-HALF SPLIT: each hop = 2 launches; pass p gathers only the 64B
// half-rows of feature range [p*64,(p+1)*64) from a 3.2MB slice -> per-XCD-L2
// resident, with phase coherence enforced by the launch boundary. Partial sums
// are FINAL for the pass's features (no cross-pass accumulation, no f32 round
// trip). Shape: 8 rows/wave, 8 lanes x 8B per row (512B/gather instr);
// zero-row sentinel at N_NODES absorbs degree divergence.
// xin/out8 point at the pass's half slab; out16 points at h3b + p*32 (u32).

__global__ __launch_bounds__(256) void propagate_half(const unsigned short* __restrict__ xin,
                                                      unsigned short* __restrict__ out8,
                                                      unsigned* __restrict__ out16,
                                                      int last, float extra,
                                                      const int* __restrict__ rowptr,
                                                      const unsigned short* __restrict__ csr_col,
                                                      const float* __restrict__ invdeg) {
    int lane = threadIdx.x & 63;
    int wave = threadIdx.x >> 6;
    int l8   = lane & 7;                 // 8B slice within the half-row (feats 8*l8..8*l8+7)
    int grp  = lane >> 3;                // row-in-wave 0..7
    int r = blockIdx.x * 32 + wave * 8 + grp;
    bool rv = (r < N_NODES);
    int rc = rv ? r : 0;
    int beg = rowptr[rc], end = rowptr[rc + 1];
    int nn = rv ? (end - beg) : 0;

    // wave-max degree (idle groups/slots read the zero row)
    int nmax = nn;
    { int t = __shfl_xor(nmax, 8, 64);  if (t > nmax) nmax = t; }
    { int t = __shfl_xor(nmax, 16, 64); if (t > nmax) nmax = t; }
    { int t = __shfl_xor(nmax, 32, 64); if (t > nmax) nmax = t; }

    f32x2 acc[4];
#pragma unroll
    for (int i = 0; i < 4; ++i) acc[i] = (f32x2){0.f, 0.f};
    {   // self loop
        uint2 u = *(const uint2*)(xin + (size_t)rc * 32 + l8 * 4);
        dec8_add(u, acc);
    }

    int base = lane & 56;
    // lane l8 holds the col index for (its group's row, batch_start + l8)
    auto ldidx = [&](int jb) -> int {
        int jj = jb + l8;
        int idx = (jj < nn) ? beg + jj : 0;
        unsigned short cl = csr_col[idx];
        return (jj < nn) ? (int)cl : N_NODES;
    };

    int cv = ldidx(0);
    for (int jb = 0; jb < nmax; jb += 8) {
        uint2 u[8];
#pragma unroll
        for (int q = 0; q < 8; ++q) {
            int c = __shfl(cv, base + q, 64);
            u[q] = *(const uint2*)(xin + (size_t)c * 32 + l8 * 4);
        }
        int cvn = ldidx(jb + 8);          // prefetch next batch indices
#pragma unroll
        for (int q = 0; q < 8; ++q) dec8_add(u[q], acc);
        cv = cvn;
    }

    if (!rv) return;

    float s = invdeg[r] * extra;
#pragma unroll
    for (int i = 0; i < 4; ++i) acc[i] *= s;

    if (last) {
        uint4 w;
        w.x = (unsigned)f2bf(acc[0].x) | ((unsigned)f2bf(acc[0].y) << 16);
        w.y = (unsigned)f2bf(acc[1].x) | ((unsigned)f2bf(acc[1].y) << 16);
        w.z = (unsigned)f2bf(acc[2].x) | ((unsigned)f2bf(acc[2].y) << 16);
        w.w = (unsigned)f2bf(acc[3].x) | ((unsigned)f2bf(acc[3].y) << 16);
        *(uint4*)(out16 + (size_t)r * 64 + l8 * 4) = w;   // out16 pre-offset by p*32
    } else {
        uint2 w;
        w.x = (unsigned)fp8x2_enc(acc[0].x, acc[0].y) | ((unsigned)fp8x2_enc(acc[1].x, acc[1].y) << 16);
        w.y = (unsigned)fp8x2_enc(acc[2].x, acc[2].y) | ((unsigned)fp8x2_enc(acc[3].x, acc[3].y) << 16);
        *(uint2*)(out8 + (size_t)r * 32 + l8 * 4) = w;
    }
}

// ---------------------------------------------------------------- MFMA GEMM + pool, register-only epilogue

__global__ __launch_bounds__(256) void gemm_graph_pool(const unsigned short* __restrict__ h3b,
                                                       const unsigned short* __restrict__ w1p,
                                                       const float* __restrict__ b1,
                                                       const int* __restrict__ gstart,
                                                       float* __restrict__ gsum) {
    __shared__ float wsum[4][128];
    int tid = threadIdx.x;
    int lane = tid & 63, wave = tid >> 6;
    int quad = lane >> 4, l15 = lane & 15;
    int g = blockIdx.x;
    int nbase = blockIdx.y * 128;
    int ms = blockIdx.z;
    int r0 = gstart[g], r1 = gstart[g + 1];

    float b1v[8];
#pragma unroll
    for (int t = 0; t < 8; ++t) b1v[t] = b1[nbase + t * 16 + l15];

    const unsigned short* bbase = w1p + ((size_t)(blockIdx.y * 8) * 4 * 64 + lane) * 8;

    float gaccT[8];
#pragma unroll
    for (int t = 0; t < 8; ++t) gaccT[t] = 0.f;

    for (int mbase = r0 + ms * 64; mbase < r1; mbase += 64 * MSPLIT) {
        int m = mbase + wave * 16 + l15;
        int mc = m < N_NODES ? m : N_NODES - 1;      // clamp; invalid rows masked below
        const unsigned short* arow = h3b + (size_t)mc * 128 + quad * 8;
        bf16x8 afrag[4];
#pragma unroll
        for (int s = 0; s < 4; ++s)
            afrag[s] = *(const bf16x8*)(arow + s * 32);

        int rowbase = mbase + wave * 16 + quad * 4;  // this lane's C rows: rowbase+rg
#pragma unroll
        for (int t = 0; t < 8; ++t) {
            f32x4 acc = (f32x4){0.f, 0.f, 0.f, 0.f};
#pragma unroll
            for (int s = 0; s < 4; ++s) {
                bf16x8 bfrag = *(const bf16x8*)(bbase + (size_t)(t * 4 + s) * 64 * 8);
                acc = __builtin_amdgcn_mfma_f32_16x16x32_bf16(afrag[s], bfrag, acc, 0, 0, 0);
            }
#pragma unroll
            for (int rg = 0; rg < 4; ++rg) {
                float v = acc[rg] + b1v[t];
                v = v > 0.f ? v : 0.f;
                gaccT[t] += (rowbase + rg < r1) ? v : 0.f;
            }
        }
    }
    // sum the 4 quads (rows 0..15 of the wave strip) per column
#pragma unroll
    for (int t = 0; t < 8; ++t) {
        gaccT[t] += __shfl_xor(gaccT[t], 16, 64);
        gaccT[t] += __shfl_xor(gaccT[t], 32, 64);
    }
    if (quad == 0) {
#pragma unroll
        for (int t = 0; t < 8; ++t)
            wsum[wave][t * 16 + l15] = gaccT[t];
    }
    __syncthreads();
    if (tid < 128)
        gsum[((size_t)ms * N_GRAPHS + g) * D_H + nbase + tid] =
            wsum[0][tid] + wsum[1][tid] + wsum[2][tid] + wsum[3][tid];
}

// ---------------------------------------------------------------- final: mean + folded (512x16) projection

__global__ __launch_bounds__(256) void final_pool(const float* __restrict__ gsum,
                                                  const int* __restrict__ gcnt,
                                                  const float* __restrict__ wcomb,
                                                  const float* __restrict__ bcomb,
                                                  float* __restrict__ out) {
    int g = blockIdx.x;
    int tid = threadIdx.x;
    __shared__ float p[D_H];
    __shared__ float part[16][17];
    int c = gcnt[g]; if (c < 1) c = 1;
    float inv = 1.0f / (float)c;
#pragma unroll
    for (int h = 0; h < 2; ++h) {
        int i = tid + h * 256;
        float v = 0.f;
#pragma unroll
        for (int ms = 0; ms < MSPLIT; ++ms)
            v += gsum[((size_t)ms * N_GRAPHS + g) * D_H + i];
        p[i] = v * inv;
    }
    __syncthreads();
    int o = tid & 15, ch = tid >> 4;
    int k0 = ch * 32;
    float s = 0.f;
    for (int k = k0; k < k0 + 32; ++k)
        s += p[k] * wcomb[k * D_OUT + o];
    part[ch][o] = s;
    __syncthreads();
    if (tid < D_OUT) {
        float t = bcomb[tid];
        for (int ch2 = 0; ch2 < 16; ++ch2) t += part[ch2][tid];
        out[g * D_OUT + tid] = t;
    }
}

// ---------------------------------------------------------------- launch

extern "C" void kernel_launch(void* const* d_in, const int* in_sizes, int n_in,
                              void* d_out, int out_size, void* d_ws, size_t ws_size,
                              hipStream_t stream) {
    const float* x     = (const float*)d_in[0];
    const int*   eidx  = (const int*)d_in[1];   // [2, E]
    const int*   batch = (const int*)d_in[2];
    const float* w1    = (const float*)d_in[3];
    const float* b1    = (const float*)d_in[4];
    const float* w2    = (const float*)d_in[5];
    const float* b2    = (const float*)d_in[6];
    const float* wc    = (const float*)d_in[7];
    const float* bc    = (const float*)d_in[8];
    float* out = (float*)d_out;
    const int* row = eidx;
    const int* col = eidx + N_EDGES;

    char* p = (char*)d_ws;
    auto alloc = [&](size_t bytes) { char* q = p; p += (bytes + 255) & ~(size_t)255; return q; };
    // zero-init region: only bucket_cnt
    char* zbase = p;
    int*   bucket_cnt = (int*)alloc((size_t)NBUK * 4);
    size_t zbytes = (size_t)(p - zbase);
    float* gsum    = (float*)alloc((size_t)MSPLIT * N_GRAPHS * D_H * 4);
    int*   rowptr  = (int*)alloc((size_t)(N_NODES + 1) * 4);
    int*   gcnt    = (int*)alloc((size_t)N_GRAPHS * 4);
    int*   gstart  = (int*)alloc((size_t)(N_GRAPHS + 1) * 4);
    float* invdeg  = (float*)alloc((size_t)N_NODES * 4);
    float* wcomb   = (float*)alloc((size_t)D_H * D_OUT * 4);
    float* bcomb   = (float*)alloc((size_t)D_OUT * 4);
    unsigned* edge_buf = (unsigned*)alloc((size_t)NBUK * BUK_CAP * 4);
    unsigned short* csr_col = (unsigned short*)alloc((size_t)N_EDGES * 2);
    unsigned short* xf  = (unsigned short*)alloc(HSTRIDE * 2 * 2);   // [2 halves][(N+1)*32] fp8x2
    unsigned short* h0f = (unsigned short*)alloc(HSTRIDE * 2 * 2);
    unsigned short* h1f = (unsigned short*)alloc(HSTRIDE * 2 * 2);
    unsigned* h3b  = (unsigned*)alloc((size_t)N_NODES * 64 * 4);     // bf16x2 node-major
    unsigned short* w1p = (unsigned short*)alloc((size_t)D_IN * D_H * 2);

    (void)hipMemsetAsync(zbase, 0, zbytes, stream);

    prep<<<12790, 256, 0, stream>>>(x, xf, w1, w1p, w2, wc, b2, bc, batch,
                                    wcomb, bcomb, gcnt, gstart, h0f, h1f);

    partition_edges<<<P1_BLOCKS, 512, 0, stream>>>(row, col, bucket_cnt, edge_buf);
    finalize_csr<<<NBUK, 512, 0, stream>>>(edge_buf, bucket_cnt, rowptr, invdeg, csr_col);

    int pgrid = (N_NODES + 31) / 32;   // 8 rows/wave, 4 waves/block
    // hop 1: two feature-half passes
    propagate_half<<<pgrid, 256, 0, stream>>>(xf,           h0f,           nullptr, 0, 8.0f,
                                              rowptr, csr_col, invdeg);
    propagate_half<<<pgrid, 256, 0, stream>>>(xf + HSTRIDE, h0f + HSTRIDE, nullptr, 0, 8.0f,
                                              rowptr, csr_col, invdeg);
    // hop 2
    propagate_half<<<pgrid, 256, 0, stream>>>(h0f,           h1f,           nullptr, 0, 8.0f,
                                              rowptr, csr_col, invdeg);
    propagate_half<<<pgrid, 256, 0, stream>>>(h0f + HSTRIDE, h1f + HSTRIDE, nullptr, 0, 8.0f,
                                              rowptr, csr_col, invdeg);
    // hop 3 (bf16 out for the GEMM; out16 pre-offset by half*32 u32)
    propagate_half<<<pgrid, 256, 0, stream>>>(h1f,           nullptr, h3b,      1, 1.0f / 64.0f,
                                              rowptr, csr_col, invdeg);
    propagate_half<<<pgrid, 256, 0, stream>>>(h1f + HSTRIDE, nullptr, h3b + 32, 1, 1.0f / 64.0f,
                                              rowptr, csr_col, invdeg);

    dim3 ggrid(N_GRAPHS, D_H / 128, MSPLIT);
    gemm_graph_pool<<<ggrid, 256, 0, stream>>>((const unsigned short*)h3b, w1p, b1,
                                               gstart, gsum);
    final_pool<<<N_GRAPHS, 256, 0, stream>>>(gsum, gcnt, wcomb, bcomb, out);
}

// Round 8
// 242.798 us; speedup vs baseline: 1.0431x; 1.0431x over previous
//
#include <hip/hip_runtime.h>
#include <hip/hip_bf16.h>
#include <hip/hip_fp8.h>

#define N_NODES 50000
#define N_EDGES 1600000
#define N_GRAPHS 64
#define D_IN 128
#define D_H 512
#define D_OUT 16

// atomic-free CSR build: buckets of 128 rows, 391 blocks for both phases
#define NBUK 391                      // ceil(50000/128)
#define BUK_CAP 4608                  // mean 4092 + ~8 sigma
#define P1_EDGES 4096                 // edges per partition block
#define P1_BLOCKS ((N_EDGES + P1_EDGES - 1) / P1_EDGES)   // 391

#define MSPLIT 8                      // M-tile interleave factor for the GEMM

typedef short bf16x8 __attribute__((ext_vector_type(8)));
typedef float f32x4 __attribute__((ext_vector_type(4)));
typedef float f32x2 __attribute__((ext_vector_type(2)));

static __device__ __forceinline__ unsigned short f2bf(float f) {
    __hip_bfloat16 h = __float2bfloat16(f);   // RNE
    return *(unsigned short*)&h;
}

static __device__ __forceinline__ float2 fp8x2_dec(unsigned short u) {
    __hip_fp8x2_e4m3 p;
    p.__x = (__hip_fp8x2_storage_t)u;
    return static_cast<float2>(p);
}

static __device__ __forceinline__ unsigned short fp8x2_enc(float a, float b) {
    __hip_fp8_e4m3 pa(a), pb(b);
    return (unsigned short)((unsigned)pa.__x | ((unsigned)pb.__x << 8));
}

// decode 16 fp8 (one uint4 = 16B slice) and accumulate into 8 packed f32x2
static __device__ __forceinline__ void dec16_add(uint4 u, f32x2* acc) {
    unsigned vv[4] = {u.x, u.y, u.z, u.w};
#pragma unroll
    for (int w = 0; w < 4; ++w) {
        float2 a = fp8x2_dec((unsigned short)(vv[w] & 0xFFFFu));
        float2 b = fp8x2_dec((unsigned short)(vv[w] >> 16));
        f32x2 av; av.x = a.x; av.y = a.y;
        f32x2 bv; bv.x = b.x; bv.y = b.y;
        acc[w * 2 + 0] += av;
        acc[w * 2 + 1] += bv;
    }
}

// ---------------------------------------------------------------- CSR build (atomic-free)
// P1: 391 blocks x 512 threads, 4096 edges each. rec = (buk:9)<<23 | (rlow:7)<<16 | col:16.

__global__ __launch_bounds__(512) void partition_edges(const int* __restrict__ row,
                                                       const int* __restrict__ col,
                                                       int* __restrict__ bucket_cnt,
                                                       unsigned* __restrict__ edge_buf) {
    __shared__ unsigned recs[P1_EDGES];     // 16 KB
    __shared__ unsigned sorted[P1_EDGES];   // 16 KB
    __shared__ int hist4[4][NBUK];          // per-wave-pair counts -> local bases
    __shared__ int cur4[4][NBUK];
    __shared__ int gbase[NBUK];
    __shared__ int scan[512];
    int tid = threadIdx.x;
    int w2 = tid >> 7;                      // wave-pair 0..3
    int e0 = blockIdx.x * P1_EDGES;
    int m = N_EDGES - e0; if (m > P1_EDGES) m = P1_EDGES;

    for (int i = tid; i < 4 * NBUK; i += 512) ((int*)hist4)[i] = 0;
    for (int i = tid; i < 4 * NBUK; i += 512) ((int*)cur4)[i] = 0;
    __syncthreads();
    for (int i = tid; i < m; i += 512) {
        int r = row[e0 + i];
        int c = col[e0 + i];
        int buk = r >> 7;
        recs[i] = ((unsigned)buk << 23) | ((unsigned)(r & 127) << 16) | (unsigned)c;
        atomicAdd(&hist4[w2][buk], 1);
    }
    __syncthreads();
    int tot = 0;
    if (tid < NBUK) tot = hist4[0][tid] + hist4[1][tid] + hist4[2][tid] + hist4[3][tid];
    scan[tid] = (tid < NBUK) ? tot : 0;
    __syncthreads();
    for (int off = 1; off < 512; off <<= 1) {
        int v = (tid >= off) ? scan[tid - off] : 0;
        __syncthreads();
        scan[tid] += v;
        __syncthreads();
    }
    if (tid < NBUK) {
        int run = (tid == 0) ? 0 : scan[tid - 1];   // block-local excl base
        gbase[tid] = (tot > 0) ? atomicAdd(&bucket_cnt[tid], tot) : 0;  // reserve range
#pragma unroll
        for (int w = 0; w < 4; ++w) {               // per-sub-group local bases
            int c = hist4[w][tid];
            hist4[w][tid] = run;
            run += c;
        }
    }
    __syncthreads();
    for (int i = tid; i < m; i += 512) {            // rank + reorder (bucket-major)
        unsigned rec = recs[i];
        int buk = rec >> 23;
        int rank = atomicAdd(&cur4[w2][buk], 1);
        sorted[hist4[w2][buk] + rank] = rec;
    }
    __syncthreads();
    for (int p = tid; p < m; p += 512) {            // coalesced-run writes
        unsigned rec = sorted[p];
        int buk = rec >> 23;
        edge_buf[(size_t)buk * BUK_CAP + gbase[buk] + (p - hist4[0][buk])] = rec;
    }
}

// P2: one block per bucket (391 x 512); inline scan of bucket_cnt; LDS-cursor scatter.
__global__ __launch_bounds__(512) void finalize_csr(const unsigned* __restrict__ edge_buf,
                                                    const int* __restrict__ bucket_cnt,
                                                    int* __restrict__ rowptr,
                                                    float* __restrict__ invdeg,
                                                    unsigned short* __restrict__ csr_col) {
    __shared__ int hist[128], excl[128], cur[128];
    __shared__ int scan[512];
    int b = blockIdx.x;
    int tid = threadIdx.x;
    scan[tid] = (tid < NBUK) ? bucket_cnt[tid] : 0;
    __syncthreads();
    for (int off = 1; off < 512; off <<= 1) {
        int v = (tid >= off) ? scan[tid - off] : 0;
        __syncthreads();
        scan[tid] += v;
        __syncthreads();
    }
    int cnt = bucket_cnt[b];
    int base = (b == 0) ? 0 : scan[b - 1];
    const unsigned* src = edge_buf + (size_t)b * BUK_CAP;
    __syncthreads();
    if (tid < 128) { hist[tid] = 0; cur[tid] = 0; }
    __syncthreads();
    for (int i = tid; i < cnt; i += 512)
        atomicAdd(&hist[(src[i] >> 16) & 127], 1);
    __syncthreads();
    scan[tid] = (tid < 128) ? hist[tid] : 0;
    __syncthreads();
    for (int off = 1; off < 512; off <<= 1) {
        int v = (tid >= off) ? scan[tid - off] : 0;
        __syncthreads();
        scan[tid] += v;
        __syncthreads();
    }
    if (tid < 128) excl[tid] = (tid == 0) ? 0 : scan[tid - 1];
    __syncthreads();
    int r = b * 128 + tid;
    if (tid < 128 && r < N_NODES) {
        rowptr[r] = base + excl[tid];
        invdeg[r] = 1.0f / (float)(hist[tid] + 1);   // +1: self loop
    }
    if (b == NBUK - 1 && tid == 0) rowptr[N_NODES] = base + cnt;
    for (int i = tid; i < cnt; i += 512) {
        unsigned rec = src[i];
        int rl = (rec >> 16) & 127;
        int pos = excl[rl] + atomicAdd(&cur[rl], 1);
        csr_col[base + pos] = (unsigned short)(rec & 0xFFFFu);
    }
}

// ---------------------------------------------------------------- merged prep
// [0,12500): convert_x; [12500,12756): make_w1p; [12756,12790): fold_w + graph bounds
// + zero-row sentinels + bucket_cnt zeroing (replaces the memset dispatch).

__global__ __launch_bounds__(256) void prep(const float* __restrict__ x,
                                            unsigned short* __restrict__ xf,
                                            const float* __restrict__ w1,
                                            unsigned short* __restrict__ w1p,
                                            const float* __restrict__ w2,
                                            const float* __restrict__ wc,
                                            const float* __restrict__ b2,
                                            const float* __restrict__ bc,
                                            const int* __restrict__ batch,
                                            float* __restrict__ wcomb,
                                            float* __restrict__ bcomb,
                                            int* __restrict__ gcnt,
                                            int* __restrict__ gstart,
                                            unsigned short* __restrict__ h0f,
                                            unsigned short* __restrict__ h1f,
                                            int* __restrict__ bucket_cnt) {
    int b = blockIdx.x;
    int tid = threadIdx.x;
    if (b < 12500) {                                // convert_x: 12500*256 == N*64 exactly
        int i = b * 256 + tid;
        float2 v = ((const float2*)x)[i];
        xf[i] = fp8x2_enc(v.x, v.y);
        return;
    }
    if (b < 12756) {                                // make_w1p: 256 blocks, 65536 elems
        int i = (b - 12500) * 256 + tid;
        int j = i & 7, lane = (i >> 3) & 63, s = (i >> 9) & 3, t = i >> 11;
        int k = s * 32 + (lane >> 4) * 8 + j;
        int n = t * 16 + (lane & 15);
        w1p[i] = f2bf(w1[(size_t)k * D_H + n]);
        return;
    }
    int fb = b - 12756;                             // fold_w blocks 0..33
    if (fb == 33) {
        for (int i = tid; i < NBUK; i += 256) bucket_cnt[i] = 0;   // replaces memset
        if (tid < N_GRAPHS) {
            int g = tid;
            int lo = 0, hi = N_NODES;
            while (lo < hi) { int mid = (lo + hi) >> 1; if (batch[mid] < g) lo = mid + 1; else hi = mid; }
            int a = lo;
            lo = 0; hi = N_NODES;
            while (lo < hi) { int mid = (lo + hi) >> 1; if (batch[mid] < g + 1) lo = mid + 1; else hi = mid; }
            gcnt[g] = lo - a;
            gstart[g] = a;
            if (g == N_GRAPHS - 1) gstart[N_GRAPHS] = N_NODES;
        } else if (tid >= 64 && tid < 256) {        // zero-row sentinels (3 bufs x 64 u16)
            int t = tid - 64;
            unsigned short* bp = (t < 64) ? xf : (t < 128 ? h0f : h1f);
            bp[(size_t)N_NODES * 64 + (t & 63)] = 0;
        }
        return;
    }
    int o = tid & 15, kl = tid >> 4;
    int k = fb * 16 + kl;
    if (k > D_H) return;
    const float* wr = (k < D_H) ? (w2 + (size_t)k * D_H) : b2;
    float s = 0.f;
    for (int j = 0; j < D_H; j += 4) {
        s += wr[j + 0] * wc[(j + 0) * D_OUT + o]
           + wr[j + 1] * wc[(j + 1) * D_OUT + o]
           + wr[j + 2] * wc[(j + 2) * D_OUT + o]
           + wr[j + 3] * wc[(j + 3) * D_OUT + o];
    }
    if (k < D_H) wcomb[k * D_OUT + o] = s;
    else         bcomb[o] = s + bc[o];
}

// ---------------------------------------------------------------- propagation (fp8 storage, f32 accumulate)
// Frozen (6 structural probes): 8 rows/wave, 16B/lane (1KB/gather), depth-2
// pipelined, zero-row sentinel. Bound by random line-request service rate
// (~40G req/s device-wide; per-REQUEST cost — R7 proved 64B requests cost the
// same as 128B). 1 request/edge is minimal -> ~40us/hop floor.

__global__ __launch_bounds__(256) void propagate_fp8(const unsigned short* __restrict__ xin,
                                                     unsigned short* __restrict__ out8,
                                                     unsigned* __restrict__ out16,
                                                     int last, float extra,
                                                     const int* __restrict__ rowptr,
                                                     const unsigned short* __restrict__ csr_col,
                                                     const float* __restrict__ invdeg) {
    int lane = threadIdx.x & 63;
    int wave = threadIdx.x >> 6;
    int l8   = lane & 7;                 // 16B slice within the row (features 16*l8..16*l8+15)
    int grp  = lane >> 3;                // row-in-wave 0..7
    int r = blockIdx.x * 32 + wave * 8 + grp;
    bool rv = (r < N_NODES);
    int rc = rv ? r : 0;
    int beg = rowptr[rc], end = rowptr[rc + 1];
    int nn = rv ? (end - beg) : 0;

    // wave-max degree (idle groups/slots read the zero row)
    int nmax = nn;
    { int t = __shfl_xor(nmax, 8, 64);  if (t > nmax) nmax = t; }
    { int t = __shfl_xor(nmax, 16, 64); if (t > nmax) nmax = t; }
    { int t = __shfl_xor(nmax, 32, 64); if (t > nmax) nmax = t; }

    f32x2 acc[8];
#pragma unroll
    for (int i = 0; i < 8; ++i) acc[i] = (f32x2){0.f, 0.f};
    {   // self loop
        uint4 u = *(const uint4*)(xin + (size_t)rc * 64 + l8 * 8);
        dec16_add(u, acc);
    }

    int base = lane & 56;
    // lane l8 holds the col index for (its group's row, batch_start + l8);
    // out-of-range slots -> zero-row sentinel (always address-safe: idx 0)
    auto ldidx = [&](int jb) -> int {
        int jj = jb + l8;
        int idx = (jj < nn) ? beg + jj : 0;
        unsigned short cl = csr_col[idx];
        return (jj < nn) ? (int)cl : N_NODES;
    };

    int nb = (nmax + 7) >> 3;                 // number of 8-edge-per-group batches
    if (nb > 0) {
        uint4 uA[8], uB[8];
        {
            int cv = ldidx(0);
#pragma unroll
            for (int q = 0; q < 8; ++q) {
                int c = __shfl(cv, base + q, 64);
                uA[q] = *(const uint4*)(xin + (size_t)c * 64 + l8 * 8);
            }
        }
        int cvn = ldidx(8);                   // indices for batch 1
        int k = 0;
        while (true) {
            // invariant: uA = batch k in flight; cvn = indices for batch k+1
            if (k + 1 < nb) {
#pragma unroll
                for (int q = 0; q < 8; ++q) {
                    int c = __shfl(cvn, base + q, 64);
                    uB[q] = *(const uint4*)(xin + (size_t)c * 64 + l8 * 8);
                }
            }
            cvn = ldidx((k + 2) * 8);         // prefetch indices for k+2 (sentinel-safe)
#pragma unroll
            for (int q = 0; q < 8; ++q) dec16_add(uA[q], acc);
            ++k;
            if (k >= nb) break;
            // invariant: uB = batch k in flight; cvn = indices for batch k+1
            if (k + 1 < nb) {
#pragma unroll
                for (int q = 0; q < 8; ++q) {
                    int c = __shfl(cvn, base + q, 64);
                    uA[q] = *(const uint4*)(xin + (size_t)c * 64 + l8 * 8);
                }
            }
            cvn = ldidx((k + 2) * 8);
#pragma unroll
            for (int q = 0; q < 8; ++q) dec16_add(uB[q], acc);
            ++k;
            if (k >= nb) break;
        }
    }

    if (!rv) return;

    float s = invdeg[r] * extra;
#pragma unroll
    for (int i = 0; i < 8; ++i) acc[i] *= s;

    if (last) {
        uint4 w0, w1v;
        w0.x = (unsigned)f2bf(acc[0].x) | ((unsigned)f2bf(acc[0].y) << 16);
        w0.y = (unsigned)f2bf(acc[1].x) | ((unsigned)f2bf(acc[1].y) << 16);
        w0.z = (unsigned)f2bf(acc[2].x) | ((unsigned)f2bf(acc[2].y) << 16);
        w0.w = (unsigned)f2bf(acc[3].x) | ((unsigned)f2bf(acc[3].y) << 16);
        w1v.x = (unsigned)f2bf(acc[4].x) | ((unsigned)f2bf(acc[4].y) << 16);
        w1v.y = (unsigned)f2bf(acc[5].x) | ((unsigned)f2bf(acc[5].y) << 16);
        w1v.z = (unsigned)f2bf(acc[6].x) | ((unsigned)f2bf(acc[6].y) << 16);
        w1v.w = (unsigned)f2bf(acc[7].x) | ((unsigned)f2bf(acc[7].y) << 16);
        unsigned* dst = out16 + (size_t)r * 64 + l8 * 8;
        *(uint4*)dst = w0;
        *(uint4*)(dst + 4) = w1v;
    } else {
        uint4 w;
        w.x = (unsigned)fp8x2_enc(acc[0].x, acc[0].y) | ((unsigned)fp8x2_enc(acc[1].x, acc[1].y) << 16);
        w.y = (unsigned)fp8x2_enc(acc[2].x, acc[2].y) | ((unsigned)fp8x2_enc(acc[3].x, acc[3].y) << 16);
        w.z = (unsigned)fp8x2_enc(acc[4].x, acc[4].y) | ((unsigned)fp8x2_enc(acc[5].x, acc[5].y) << 16);
        w.w = (unsigned)fp8x2_enc(acc[6].x, acc[6].y) | ((unsigned)fp8x2_enc(acc[7].x, acc[7].y) << 16);
        *(uint4*)(out8 + (size_t)r * 64 + l8 * 8) = w;
    }
}

// ---------------------------------------------------------------- MFMA GEMM + pool
// NOW 2 column-groups (256 cols) per block: A-fragments read once, used for
// both groups -> h3b traffic halves (51->26MB). grid (64, 2, MSPLIT) = 1024
// blocks (4/CU). Pool epilogue unchanged (reg-sum + shfl + 4KB LDS).

__global__ __launch_bounds__(256) void gemm_graph_pool(const unsigned short* __restrict__ h3b,
                                                       const unsigned short* __restrict__ w1p,
                                                       const float* __restrict__ b1,
                                                       const int* __restrict__ gstart,
                                                       float* __restrict__ gsum) {
    __shared__ float wsum[4][256];
    int tid = threadIdx.x;
    int lane = tid & 63, wave = tid >> 6;
    int quad = lane >> 4, l15 = lane & 15;
    int g = blockIdx.x;
    int by = blockIdx.y;                 // 256-col super-group
    int ms = blockIdx.z;
    int r0 = gstart[g], r1 = gstart[g + 1];

    float b1v[2][8];
#pragma unroll
    for (int cg = 0; cg < 2; ++cg)
#pragma unroll
        for (int t = 0; t < 8; ++t)
            b1v[cg][t] = b1[by * 256 + cg * 128 + t * 16 + l15];

    const unsigned short* bb0 = w1p + ((size_t)((by * 2 + 0) * 8) * 4 * 64 + lane) * 8;
    const unsigned short* bb1 = w1p + ((size_t)((by * 2 + 1) * 8) * 4 * 64 + lane) * 8;

    float gaccT[2][8];
#pragma unroll
    for (int cg = 0; cg < 2; ++cg)
#pragma unroll
        for (int t = 0; t < 8; ++t) gaccT[cg][t] = 0.f;

    for (int mbase = r0 + ms * 64; mbase < r1; mbase += 64 * MSPLIT) {
        int m = mbase + wave * 16 + l15;
        int mc = m < N_NODES ? m : N_NODES - 1;      // clamp; invalid rows masked below
        const unsigned short* arow = h3b + (size_t)mc * 128 + quad * 8;
        bf16x8 afrag[4];
#pragma unroll
        for (int s = 0; s < 4; ++s)
            afrag[s] = *(const bf16x8*)(arow + s * 32);

        int rowbase = mbase + wave * 16 + quad * 4;  // this lane's C rows: rowbase+rg
#pragma unroll
        for (int cg = 0; cg < 2; ++cg) {
            const unsigned short* bbase = cg ? bb1 : bb0;
#pragma unroll
            for (int t = 0; t < 8; ++t) {
                f32x4 acc = (f32x4){0.f, 0.f, 0.f, 0.f};
#pragma unroll
                for (int s = 0; s < 4; ++s) {
                    bf16x8 bfrag = *(const bf16x8*)(bbase + (size_t)(t * 4 + s) * 64 * 8);
                    acc = __builtin_amdgcn_mfma_f32_16x16x32_bf16(afrag[s], bfrag, acc, 0, 0, 0);
                }
#pragma unroll
                for (int rg = 0; rg < 4; ++rg) {
                    float v = acc[rg] + b1v[cg][t];
                    v = v > 0.f ? v : 0.f;
                    gaccT[cg][t] += (rowbase + rg < r1) ? v : 0.f;
                }
            }
        }
    }
    // sum the 4 quads (rows 0..15 of the wave strip) per column
#pragma unroll
    for (int cg = 0; cg < 2; ++cg)
#pragma unroll
        for (int t = 0; t < 8; ++t) {
            gaccT[cg][t] += __shfl_xor(gaccT[cg][t], 16, 64);
            gaccT[cg][t] += __shfl_xor(gaccT[cg][t], 32, 64);
        }
    if (quad == 0) {
#pragma unroll
        for (int cg = 0; cg < 2; ++cg)
#pragma unroll
            for (int t = 0; t < 8; ++t)
                wsum[wave][cg * 128 + t * 16 + l15] = gaccT[cg][t];
    }
    __syncthreads();
    gsum[((size_t)ms * N_GRAPHS + g) * D_H + by * 256 + tid] =
        wsum[0][tid] + wsum[1][tid] + wsum[2][tid] + wsum[3][tid];
}

// ---------------------------------------------------------------- final: mean + folded (512x16) projection

__global__ __launch_bounds__(256) void final_pool(const float* __restrict__ gsum,
                                                  const int* __restrict__ gcnt,
                                                  const float* __restrict__ wcomb,
                                                  const float* __restrict__ bcomb,
                                                  float* __restrict__ out) {
    int g = blockIdx.x;
    int tid = threadIdx.x;
    __shared__ float p[D_H];
    __shared__ float part[16][17];
    int c = gcnt[g]; if (c < 1) c = 1;
    float inv = 1.0f / (float)c;
#pragma unroll
    for (int h = 0; h < 2; ++h) {
        int i = tid + h * 256;
        float v = 0.f;
#pragma unroll
        for (int ms = 0; ms < MSPLIT; ++ms)
            v += gsum[((size_t)ms * N_GRAPHS + g) * D_H + i];
        p[i] = v * inv;
    }
    __syncthreads();
    int o = tid & 15, ch = tid >> 4;
    int k0 = ch * 32;
    float s = 0.f;
    for (int k = k0; k < k0 + 32; ++k)
        s += p[k] * wcomb[k * D_OUT + o];
    part[ch][o] = s;
    __syncthreads();
    if (tid < D_OUT) {
        float t = bcomb[tid];
        for (int ch2 = 0; ch2 < 16; ++ch2) t += part[ch2][tid];
        out[g * D_OUT + tid] = t;
    }
}

// ---------------------------------------------------------------- launch

extern "C" void kernel_launch(void* const* d_in, const int* in_sizes, int n_in,
                              void* d_out, int out_size, void* d_ws, size_t ws_size,
                              hipStream_t stream) {
    const float* x     = (const float*)d_in[0];
    const int*   eidx  = (const int*)d_in[1];   // [2, E]
    const int*   batch = (const int*)d_in[2];
    const float* w1    = (const float*)d_in[3];
    const float* b1    = (const float*)d_in[4];
    const float* w2    = (const float*)d_in[5];
    const float* b2    = (const float*)d_in[6];
    const float* wc    = (const float*)d_in[7];
    const float* bc    = (const float*)d_in[8];
    float* out = (float*)d_out;
    const int* row = eidx;
    const int* col = eidx + N_EDGES;

    char* p = (char*)d_ws;
    auto alloc = [&](size_t bytes) { char* q = p; p += (bytes + 255) & ~(size_t)255; return q; };
    int*   bucket_cnt = (int*)alloc((size_t)NBUK * 4);    // zeroed by prep
    float* gsum    = (float*)alloc((size_t)MSPLIT * N_GRAPHS * D_H * 4);
    int*   rowptr  = (int*)alloc((size_t)(N_NODES + 1) * 4);
    int*   gcnt    = (int*)alloc((size_t)N_GRAPHS * 4);
    int*   gstart  = (int*)alloc((size_t)(N_GRAPHS + 1) * 4);
    float* invdeg  = (float*)alloc((size_t)N_NODES * 4);
    float* wcomb   = (float*)alloc((size_t)D_H * D_OUT * 4);
    float* bcomb   = (float*)alloc((size_t)D_OUT * 4);
    unsigned* edge_buf = (unsigned*)alloc((size_t)NBUK * BUK_CAP * 4);
    unsigned short* csr_col = (unsigned short*)alloc((size_t)N_EDGES * 2);
    unsigned short* xf  = (unsigned short*)alloc((size_t)(N_NODES + 1) * 64 * 2);  // fp8x2 + zero row
    unsigned short* h0f = (unsigned short*)alloc((size_t)(N_NODES + 1) * 64 * 2);  // fp8x2 + zero row
    unsigned short* h1f = (unsigned short*)alloc((size_t)(N_NODES + 1) * 64 * 2);  // fp8x2 + zero row
    unsigned* h3b  = (unsigned*)alloc((size_t)N_NODES * 64 * 4);                   // bf16x2 node-major
    unsigned short* w1p = (unsigned short*)alloc((size_t)D_IN * D_H * 2);

    prep<<<12790, 256, 0, stream>>>(x, xf, w1, w1p, w2, wc, b2, bc, batch,
                                    wcomb, bcomb, gcnt, gstart, h0f, h1f, bucket_cnt);

    partition_edges<<<P1_BLOCKS, 512, 0, stream>>>(row, col, bucket_cnt, edge_buf);
    finalize_csr<<<NBUK, 512, 0, stream>>>(edge_buf, bucket_cnt, rowptr, invdeg, csr_col);

    int pgrid = (N_NODES + 31) / 32;   // 8 rows/wave, 4 waves/block
    propagate_fp8<<<pgrid, 256, 0, stream>>>(xf,  h0f, nullptr, 0, 8.0f,
                                             rowptr, csr_col, invdeg);
    propagate_fp8<<<pgrid, 256, 0, stream>>>(h0f, h1f, nullptr, 0, 8.0f,
                                             rowptr, csr_col, invdeg);
    propagate_fp8<<<pgrid, 256, 0, stream>>>(h1f, nullptr, h3b, 1, 1.0f / 64.0f,
                                             rowptr, csr_col, invdeg);

    dim3 ggrid(N_GRAPHS, 2, MSPLIT);
    gemm_graph_pool<<<ggrid, 256, 0, stream>>>((const unsigned short*)h3b, w1p, b1,
                                               gstart, gsum);
    final_pool<<<N_GRAPHS, 256, 0, stream>>>(gsum, gcnt, wcomb, bcomb, out);
}

// Round 9
// 230.743 us; speedup vs baseline: 1.0976x; 1.0522x over previous
//
#include <hip/hip_runtime.h>
#include <hip/hip_bf16.h>
#include <hip/hip_fp8.h>

#define N_NODES 50000
#define N_EDGES 1600000
#define N_GRAPHS 64
#define D_IN 128
#define D_H 512
#define D_OUT 16

// atomic-free CSR build: buckets of 128 rows, 391 blocks for both phases
#define NBUK 391                      // ceil(50000/128)
#define BUK_CAP 4608                  // mean 4092 + ~8 sigma
#define P1_EDGES 4096                 // edges per partition block
#define P1_BLOCKS ((N_EDGES + P1_EDGES - 1) / P1_EDGES)   // 391

#define MSPLIT 8                      // M-tile interleave factor for the GEMM

typedef short bf16x8 __attribute__((ext_vector_type(8)));
typedef float f32x4 __attribute__((ext_vector_type(4)));
typedef float f32x2 __attribute__((ext_vector_type(2)));

static __device__ __forceinline__ unsigned short f2bf(float f) {
    __hip_bfloat16 h = __float2bfloat16(f);   // RNE
    return *(unsigned short*)&h;
}

static __device__ __forceinline__ float2 fp8x2_dec(unsigned short u) {
    __hip_fp8x2_e4m3 p;
    p.__x = (__hip_fp8x2_storage_t)u;
    return static_cast<float2>(p);
}

static __device__ __forceinline__ unsigned short fp8x2_enc(float a, float b) {
    __hip_fp8_e4m3 pa(a), pb(b);
    return (unsigned short)((unsigned)pa.__x | ((unsigned)pb.__x << 8));
}

// decode 16 fp8 (one uint4 = 16B slice) and accumulate into 8 packed f32x2
// (acc[w*2+0] = feats 4w+0,4w+1; acc[w*2+1] = feats 4w+2,4w+3) -> v_pk_add_f32
static __device__ __forceinline__ void dec16_add(uint4 u, f32x2* acc) {
    unsigned vv[4] = {u.x, u.y, u.z, u.w};
#pragma unroll
    for (int w = 0; w < 4; ++w) {
        float2 a = fp8x2_dec((unsigned short)(vv[w] & 0xFFFFu));
        float2 b = fp8x2_dec((unsigned short)(vv[w] >> 16));
        f32x2 av; av.x = a.x; av.y = a.y;
        f32x2 bv; bv.x = b.x; bv.y = b.y;
        acc[w * 2 + 0] += av;
        acc[w * 2 + 1] += bv;
    }
}

// ---------------------------------------------------------------- CSR build (atomic-free)
// P1: 391 blocks x 512 threads, 4096 edges each. rec = (buk:9)<<23 | (rlow:7)<<16 | col:16.

__global__ __launch_bounds__(512) void partition_edges(const int* __restrict__ row,
                                                       const int* __restrict__ col,
                                                       int* __restrict__ bucket_cnt,
                                                       unsigned* __restrict__ edge_buf) {
    __shared__ unsigned recs[P1_EDGES];     // 16 KB
    __shared__ unsigned sorted[P1_EDGES];   // 16 KB
    __shared__ int hist4[4][NBUK];          // per-wave-pair counts -> local bases
    __shared__ int cur4[4][NBUK];
    __shared__ int gbase[NBUK];
    __shared__ int scan[512];
    int tid = threadIdx.x;
    int w2 = tid >> 7;                      // wave-pair 0..3
    int e0 = blockIdx.x * P1_EDGES;
    int m = N_EDGES - e0; if (m > P1_EDGES) m = P1_EDGES;

    for (int i = tid; i < 4 * NBUK; i += 512) ((int*)hist4)[i] = 0;
    for (int i = tid; i < 4 * NBUK; i += 512) ((int*)cur4)[i] = 0;
    __syncthreads();
    for (int i = tid; i < m; i += 512) {
        int r = row[e0 + i];
        int c = col[e0 + i];
        int buk = r >> 7;
        recs[i] = ((unsigned)buk << 23) | ((unsigned)(r & 127) << 16) | (unsigned)c;
        atomicAdd(&hist4[w2][buk], 1);
    }
    __syncthreads();
    int tot = 0;
    if (tid < NBUK) tot = hist4[0][tid] + hist4[1][tid] + hist4[2][tid] + hist4[3][tid];
    scan[tid] = (tid < NBUK) ? tot : 0;
    __syncthreads();
    for (int off = 1; off < 512; off <<= 1) {
        int v = (tid >= off) ? scan[tid - off] : 0;
        __syncthreads();
        scan[tid] += v;
        __syncthreads();
    }
    if (tid < NBUK) {
        int run = (tid == 0) ? 0 : scan[tid - 1];   // block-local excl base
        gbase[tid] = (tot > 0) ? atomicAdd(&bucket_cnt[tid], tot) : 0;  // reserve range
#pragma unroll
        for (int w = 0; w < 4; ++w) {               // per-sub-group local bases
            int c = hist4[w][tid];
            hist4[w][tid] = run;
            run += c;
        }
    }
    __syncthreads();
    for (int i = tid; i < m; i += 512) {            // rank + reorder (bucket-major)
        unsigned rec = recs[i];
        int buk = rec >> 23;
        int rank = atomicAdd(&cur4[w2][buk], 1);
        sorted[hist4[w2][buk] + rank] = rec;
    }
    __syncthreads();
    for (int p = tid; p < m; p += 512) {            // coalesced-run writes
        unsigned rec = sorted[p];
        int buk = rec >> 23;
        edge_buf[(size_t)buk * BUK_CAP + gbase[buk] + (p - hist4[0][buk])] = rec;
    }
}

// P2: one block per bucket (391 x 512); inline scan of bucket_cnt; LDS-cursor scatter.
__global__ __launch_bounds__(512) void finalize_csr(const unsigned* __restrict__ edge_buf,
                                                    const int* __restrict__ bucket_cnt,
                                                    int* __restrict__ rowptr,
                                                    float* __restrict__ invdeg,
                                                    unsigned short* __restrict__ csr_col) {
    __shared__ int hist[128], excl[128], cur[128];
    __shared__ int scan[512];
    int b = blockIdx.x;
    int tid = threadIdx.x;
    scan[tid] = (tid < NBUK) ? bucket_cnt[tid] : 0;
    __syncthreads();
    for (int off = 1; off < 512; off <<= 1) {
        int v = (tid >= off) ? scan[tid - off] : 0;
        __syncthreads();
        scan[tid] += v;
        __syncthreads();
    }
    int cnt = bucket_cnt[b];
    int base = (b == 0) ? 0 : scan[b - 1];
    const unsigned* src = edge_buf + (size_t)b * BUK_CAP;
    __syncthreads();
    if (tid < 128) { hist[tid] = 0; cur[tid] = 0; }
    __syncthreads();
    for (int i = tid; i < cnt; i += 512)
        atomicAdd(&hist[(src[i] >> 16) & 127], 1);
    __syncthreads();
    scan[tid] = (tid < 128) ? hist[tid] : 0;
    __syncthreads();
    for (int off = 1; off < 512; off <<= 1) {
        int v = (tid >= off) ? scan[tid - off] : 0;
        __syncthreads();
        scan[tid] += v;
        __syncthreads();
    }
    if (tid < 128) excl[tid] = (tid == 0) ? 0 : scan[tid - 1];
    __syncthreads();
    int r = b * 128 + tid;
    if (tid < 128 && r < N_NODES) {
        rowptr[r] = base + excl[tid];
        invdeg[r] = 1.0f / (float)(hist[tid] + 1);   // +1: self loop
    }
    if (b == NBUK - 1 && tid == 0) rowptr[N_NODES] = base + cnt;
    for (int i = tid; i < cnt; i += 512) {
        unsigned rec = src[i];
        int rl = (rec >> 16) & 127;
        int pos = excl[rl] + atomicAdd(&cur[rl], 1);
        csr_col[base + pos] = (unsigned short)(rec & 0xFFFFu);
    }
}

// ---------------------------------------------------------------- merged prep
// [0,12500): convert_x; [12500,12756): make_w1p; [12756,12790): fold_w + graph bounds
// + zero-row sentinels + bucket_cnt zeroing (replaces the memset dispatch).

__global__ __launch_bounds__(256) void prep(const float* __restrict__ x,
                                            unsigned short* __restrict__ xf,
                                            const float* __restrict__ w1,
                                            unsigned short* __restrict__ w1p,
                                            const float* __restrict__ w2,
                                            const float* __restrict__ wc,
                                            const float* __restrict__ b2,
                                            const float* __restrict__ bc,
                                            const int* __restrict__ batch,
                                            float* __restrict__ wcomb,
                                            float* __restrict__ bcomb,
                                            int* __restrict__ gcnt,
                                            int* __restrict__ gstart,
                                            unsigned short* __restrict__ h0f,
                                            unsigned short* __restrict__ h1f,
                                            int* __restrict__ bucket_cnt) {
    int b = blockIdx.x;
    int tid = threadIdx.x;
    if (b < 12500) {                                // convert_x: 12500*256 == N*64 exactly
        int i = b * 256 + tid;
        float2 v = ((const float2*)x)[i];
        xf[i] = fp8x2_enc(v.x, v.y);
        return;
    }
    if (b < 12756) {                                // make_w1p: 256 blocks, 65536 elems
        int i = (b - 12500) * 256 + tid;
        int j = i & 7, lane = (i >> 3) & 63, s = (i >> 9) & 3, t = i >> 11;
        int k = s * 32 + (lane >> 4) * 8 + j;
        int n = t * 16 + (lane & 15);
        w1p[i] = f2bf(w1[(size_t)k * D_H + n]);
        return;
    }
    int fb = b - 12756;                             // fold_w blocks 0..33
    if (fb == 33) {
        for (int i = tid; i < NBUK; i += 256) bucket_cnt[i] = 0;   // replaces memset
        if (tid < N_GRAPHS) {
            int g = tid;
            int lo = 0, hi = N_NODES;
            while (lo < hi) { int mid = (lo + hi) >> 1; if (batch[mid] < g) lo = mid + 1; else hi = mid; }
            int a = lo;
            lo = 0; hi = N_NODES;
            while (lo < hi) { int mid = (lo + hi) >> 1; if (batch[mid] < g + 1) lo = mid + 1; else hi = mid; }
            gcnt[g] = lo - a;
            gstart[g] = a;
            if (g == N_GRAPHS - 1) gstart[N_GRAPHS] = N_NODES;
        } else if (tid >= 64 && tid < 256) {        // zero-row sentinels (3 bufs x 64 u16)
            int t = tid - 64;
            unsigned short* bp = (t < 64) ? xf : (t < 128 ? h0f : h1f);
            bp[(size_t)N_NODES * 64 + (t & 63)] = 0;
        }
        return;
    }
    int o = tid & 15, kl = tid >> 4;
    int k = fb * 16 + kl;
    if (k > D_H) return;
    const float* wr = (k < D_H) ? (w2 + (size_t)k * D_H) : b2;
    float s = 0.f;
    for (int j = 0; j < D_H; j += 4) {
        s += wr[j + 0] * wc[(j + 0) * D_OUT + o]
           + wr[j + 1] * wc[(j + 1) * D_OUT + o]
           + wr[j + 2] * wc[(j + 2) * D_OUT + o]
           + wr[j + 3] * wc[(j + 3) * D_OUT + o];
    }
    if (k < D_H) wcomb[k * D_OUT + o] = s;
    else         bcomb[o] = s + bc[o];
}

// ---------------------------------------------------------------- propagation (fp8 storage, f32 accumulate)
// FROZEN (7 structural probes): 8 rows/wave, 16B/lane (1KB/gather), depth-2
// pipelined, zero-row sentinel. Bound by random line-request service rate
// (~40G req/s device-wide; per-REQUEST cost — R7 proved 64B requests cost the
// same as 128B). 1 request/edge is minimal -> ~40us/hop floor.

__global__ __launch_bounds__(256) void propagate_fp8(const unsigned short* __restrict__ xin,
                                                     unsigned short* __restrict__ out8,
                                                     unsigned* __restrict__ out16,
                                                     int last, float extra,
                                                     const int* __restrict__ rowptr,
                                                     const unsigned short* __restrict__ csr_col,
                                                     const float* __restrict__ invdeg) {
    int lane = threadIdx.x & 63;
    int wave = threadIdx.x >> 6;
    int l8   = lane & 7;                 // 16B slice within the row (features 16*l8..16*l8+15)
    int grp  = lane >> 3;                // row-in-wave 0..7
    int r = blockIdx.x * 32 + wave * 8 + grp;
    bool rv = (r < N_NODES);
    int rc = rv ? r : 0;
    int beg = rowptr[rc], end = rowptr[rc + 1];
    int nn = rv ? (end - beg) : 0;

    // wave-max degree (idle groups/slots read the zero row)
    int nmax = nn;
    { int t = __shfl_xor(nmax, 8, 64);  if (t > nmax) nmax = t; }
    { int t = __shfl_xor(nmax, 16, 64); if (t > nmax) nmax = t; }
    { int t = __shfl_xor(nmax, 32, 64); if (t > nmax) nmax = t; }

    f32x2 acc[8];
#pragma unroll
    for (int i = 0; i < 8; ++i) acc[i] = (f32x2){0.f, 0.f};
    {   // self loop
        uint4 u = *(const uint4*)(xin + (size_t)rc * 64 + l8 * 8);
        dec16_add(u, acc);
    }

    int base = lane & 56;
    // lane l8 holds the col index for (its group's row, batch_start + l8);
    // out-of-range slots -> zero-row sentinel (always address-safe: idx 0)
    auto ldidx = [&](int jb) -> int {
        int jj = jb + l8;
        int idx = (jj < nn) ? beg + jj : 0;
        unsigned short cl = csr_col[idx];
        return (jj < nn) ? (int)cl : N_NODES;
    };

    int nb = (nmax + 7) >> 3;                 // number of 8-edge-per-group batches
    if (nb > 0) {
        uint4 uA[8], uB[8];
        {
            int cv = ldidx(0);
#pragma unroll
            for (int q = 0; q < 8; ++q) {
                int c = __shfl(cv, base + q, 64);
                uA[q] = *(const uint4*)(xin + (size_t)c * 64 + l8 * 8);
            }
        }
        int cvn = ldidx(8);                   // indices for batch 1
        int k = 0;
        while (true) {
            // invariant: uA = batch k in flight; cvn = indices for batch k+1
            if (k + 1 < nb) {
#pragma unroll
                for (int q = 0; q < 8; ++q) {
                    int c = __shfl(cvn, base + q, 64);
                    uB[q] = *(const uint4*)(xin + (size_t)c * 64 + l8 * 8);
                }
            }
            cvn = ldidx((k + 2) * 8);         // prefetch indices for k+2 (sentinel-safe)
#pragma unroll
            for (int q = 0; q < 8; ++q) dec16_add(uA[q], acc);
            ++k;
            if (k >= nb) break;
            // invariant: uB = batch k in flight; cvn = indices for batch k+1
            if (k + 1 < nb) {
#pragma unroll
                for (int q = 0; q < 8; ++q) {
                    int c = __shfl(cvn, base + q, 64);
                    uA[q] = *(const uint4*)(xin + (size_t)c * 64 + l8 * 8);
                }
            }
            cvn = ldidx((k + 2) * 8);
#pragma unroll
            for (int q = 0; q < 8; ++q) dec16_add(uB[q], acc);
            ++k;
            if (k >= nb) break;
        }
    }

    if (!rv) return;

    float s = invdeg[r] * extra;
#pragma unroll
    for (int i = 0; i < 8; ++i) acc[i] *= s;

    if (last) {
        uint4 w0, w1v;
        w0.x = (unsigned)f2bf(acc[0].x) | ((unsigned)f2bf(acc[0].y) << 16);
        w0.y = (unsigned)f2bf(acc[1].x) | ((unsigned)f2bf(acc[1].y) << 16);
        w0.z = (unsigned)f2bf(acc[2].x) | ((unsigned)f2bf(acc[2].y) << 16);
        w0.w = (unsigned)f2bf(acc[3].x) | ((unsigned)f2bf(acc[3].y) << 16);
        w1v.x = (unsigned)f2bf(acc[4].x) | ((unsigned)f2bf(acc[4].y) << 16);
        w1v.y = (unsigned)f2bf(acc[5].x) | ((unsigned)f2bf(acc[5].y) << 16);
        w1v.z = (unsigned)f2bf(acc[6].x) | ((unsigned)f2bf(acc[6].y) << 16);
        w1v.w = (unsigned)f2bf(acc[7].x) | ((unsigned)f2bf(acc[7].y) << 16);
        unsigned* dst = out16 + (size_t)r * 64 + l8 * 8;
        *(uint4*)dst = w0;
        *(uint4*)(dst + 4) = w1v;
    } else {
        uint4 w;
        w.x = (unsigned)fp8x2_enc(acc[0].x, acc[0].y) | ((unsigned)fp8x2_enc(acc[1].x, acc[1].y) << 16);
        w.y = (unsigned)fp8x2_enc(acc[2].x, acc[2].y) | ((unsigned)fp8x2_enc(acc[3].x, acc[3].y) << 16);
        w.z = (unsigned)fp8x2_enc(acc[4].x, acc[4].y) | ((unsigned)fp8x2_enc(acc[5].x, acc[5].y) << 16);
        w.w = (unsigned)fp8x2_enc(acc[6].x, acc[6].y) | ((unsigned)fp8x2_enc(acc[7].x, acc[7].y) << 16);
        *(uint4*)(out8 + (size_t)r * 64 + l8 * 8) = w;
    }
}

// ---------------------------------------------------------------- MFMA GEMM + pool, register-only epilogue
// R5-exact: grid (64 graphs, 4 col-groups, MSPLIT) = 2048 blocks (8/CU).
// (R8's 2-col-group variant regressed — +16 VGPR / serialized MFMA runs.)

__global__ __launch_bounds__(256) void gemm_graph_pool(const unsigned short* __restrict__ h3b,
                                                       const unsigned short* __restrict__ w1p,
                                                       const float* __restrict__ b1,
                                                       const int* __restrict__ gstart,
                                                       float* __restrict__ gsum) {
    __shared__ float wsum[4][128];
    int tid = threadIdx.x;
    int lane = tid & 63, wave = tid >> 6;
    int quad = lane >> 4, l15 = lane & 15;
    int g = blockIdx.x;
    int nbase = blockIdx.y * 128;
    int ms = blockIdx.z;
    int r0 = gstart[g], r1 = gstart[g + 1];

    float b1v[8];
#pragma unroll
    for (int t = 0; t < 8; ++t) b1v[t] = b1[nbase + t * 16 + l15];

    const unsigned short* bbase = w1p + ((size_t)(blockIdx.y * 8) * 4 * 64 + lane) * 8;

    float gaccT[8];
#pragma unroll
    for (int t = 0; t < 8; ++t) gaccT[t] = 0.f;

    for (int mbase = r0 + ms * 64; mbase < r1; mbase += 64 * MSPLIT) {
        int m = mbase + wave * 16 + l15;
        int mc = m < N_NODES ? m : N_NODES - 1;      // clamp; invalid rows masked below
        const unsigned short* arow = h3b + (size_t)mc * 128 + quad * 8;
        bf16x8 afrag[4];
#pragma unroll
        for (int s = 0; s < 4; ++s)
            afrag[s] = *(const bf16x8*)(arow + s * 32);

        int rowbase = mbase + wave * 16 + quad * 4;  // this lane's C rows: rowbase+rg
#pragma unroll
        for (int t = 0; t < 8; ++t) {
            f32x4 acc = (f32x4){0.f, 0.f, 0.f, 0.f};
#pragma unroll
            for (int s = 0; s < 4; ++s) {
                bf16x8 bfrag = *(const bf16x8*)(bbase + (size_t)(t * 4 + s) * 64 * 8);
                acc = __builtin_amdgcn_mfma_f32_16x16x32_bf16(afrag[s], bfrag, acc, 0, 0, 0);
            }
#pragma unroll
            for (int rg = 0; rg < 4; ++rg) {
                float v = acc[rg] + b1v[t];
                v = v > 0.f ? v : 0.f;
                gaccT[t] += (rowbase + rg < r1) ? v : 0.f;
            }
        }
    }
    // sum the 4 quads (rows 0..15 of the wave strip) per column
#pragma unroll
    for (int t = 0; t < 8; ++t) {
        gaccT[t] += __shfl_xor(gaccT[t], 16, 64);
        gaccT[t] += __shfl_xor(gaccT[t], 32, 64);
    }
    if (quad == 0) {
#pragma unroll
        for (int t = 0; t < 8; ++t)
            wsum[wave][t * 16 + l15] = gaccT[t];
    }
    __syncthreads();
    if (tid < 128)
        gsum[((size_t)ms * N_GRAPHS + g) * D_H + nbase + tid] =
            wsum[0][tid] + wsum[1][tid] + wsum[2][tid] + wsum[3][tid];
}

// ---------------------------------------------------------------- final: mean + folded (512x16) projection

__global__ __launch_bounds__(256) void final_pool(const float* __restrict__ gsum,
                                                  const int* __restrict__ gcnt,
                                                  const float* __restrict__ wcomb,
                                                  const float* __restrict__ bcomb,
                                                  float* __restrict__ out) {
    int g = blockIdx.x;
    int tid = threadIdx.x;
    __shared__ float p[D_H];
    __shared__ float part[16][17];
    int c = gcnt[g]; if (c < 1) c = 1;
    float inv = 1.0f / (float)c;
#pragma unroll
    for (int h = 0; h < 2; ++h) {
        int i = tid + h * 256;
        float v = 0.f;
#pragma unroll
        for (int ms = 0; ms < MSPLIT; ++ms)
            v += gsum[((size_t)ms * N_GRAPHS + g) * D_H + i];
        p[i] = v * inv;
    }
    __syncthreads();
    int o = tid & 15, ch = tid >> 4;
    int k0 = ch * 32;
    float s = 0.f;
    for (int k = k0; k < k0 + 32; ++k)
        s += p[k] * wcomb[k * D_OUT + o];
    part[ch][o] = s;
    __syncthreads();
    if (tid < D_OUT) {
        float t = bcomb[tid];
        for (int ch2 = 0; ch2 < 16; ++ch2) t += part[ch2][tid];
        out[g * D_OUT + tid] = t;
    }
}

// ---------------------------------------------------------------- launch

extern "C" void kernel_launch(void* const* d_in, const int* in_sizes, int n_in,
                              void* d_out, int out_size, void* d_ws, size_t ws_size,
                              hipStream_t stream) {
    const float* x     = (const float*)d_in[0];
    const int*   eidx  = (const int*)d_in[1];   // [2, E]
    const int*   batch = (const int*)d_in[2];
    const float* w1    = (const float*)d_in[3];
    const float* b1    = (const float*)d_in[4];
    const float* w2    = (const float*)d_in[5];
    const float* b2    = (const float*)d_in[6];
    const float* wc    = (const float*)d_in[7];
    const float* bc    = (const float*)d_in[8];
    float* out = (float*)d_out;
    const int* row = eidx;
    const int* col = eidx + N_EDGES;

    char* p = (char*)d_ws;
    auto alloc = [&](size_t bytes) { char* q = p; p += (bytes + 255) & ~(size_t)255; return q; };
    int*   bucket_cnt = (int*)alloc((size_t)NBUK * 4);    // zeroed by prep
    float* gsum    = (float*)alloc((size_t)MSPLIT * N_GRAPHS * D_H * 4);
    int*   rowptr  = (int*)alloc((size_t)(N_NODES + 1) * 4);
    int*   gcnt    = (int*)alloc((size_t)N_GRAPHS * 4);
    int*   gstart  = (int*)alloc((size_t)(N_GRAPHS + 1) * 4);
    float* invdeg  = (float*)alloc((size_t)N_NODES * 4);
    float* wcomb   = (float*)alloc((size_t)D_H * D_OUT * 4);
    float* bcomb   = (float*)alloc((size_t)D_OUT * 4);
    unsigned* edge_buf = (unsigned*)alloc((size_t)NBUK * BUK_CAP * 4);
    unsigned short* csr_col = (unsigned short*)alloc((size_t)N_EDGES * 2);
    unsigned short* xf  = (unsigned short*)alloc((size_t)(N_NODES + 1) * 64 * 2);  // fp8x2 + zero row
    unsigned short* h0f = (unsigned short*)alloc((size_t)(N_NODES + 1) * 64 * 2);  // fp8x2 + zero row
    unsigned short* h1f = (unsigned short*)alloc((size_t)(N_NODES + 1) * 64 * 2);  // fp8x2 + zero row
    unsigned* h3b  = (unsigned*)alloc((size_t)N_NODES * 64 * 4);                   // bf16x2 node-major
    unsigned short* w1p = (unsigned short*)alloc((size_t)D_IN * D_H * 2);

    prep<<<12790, 256, 0, stream>>>(x, xf, w1, w1p, w2, wc, b2, bc, batch,
                                    wcomb, bcomb, gcnt, gstart, h0f, h1f, bucket_cnt);

    partition_edges<<<P1_BLOCKS, 512, 0, stream>>>(row, col, bucket_cnt, edge_buf);
    finalize_csr<<<NBUK, 512, 0, stream>>>(edge_buf, bucket_cnt, rowptr, invdeg, csr_col);

    int pgrid = (N_NODES + 31) / 32;   // 8 rows/wave, 4 waves/block
    propagate_fp8<<<pgrid, 256, 0, stream>>>(xf,  h0f, nullptr, 0, 8.0f,
                                             rowptr, csr_col, invdeg);
    propagate_fp8<<<pgrid, 256, 0, stream>>>(h0f, h1f, nullptr, 0, 8.0f,
                                             rowptr, csr_col, invdeg);
    propagate_fp8<<<pgrid, 256, 0, stream>>>(h1f, nullptr, h3b, 1, 1.0f / 64.0f,
                                             rowptr, csr_col, invdeg);

    dim3 ggrid(N_GRAPHS, D_H / 128, MSPLIT);
    gemm_graph_pool<<<ggrid, 256, 0, stream>>>((const unsigned short*)h3b, w1p, b1,
                                               gstart, gsum);
    final_pool<<<N_GRAPHS, 256, 0, stream>>>(gsum, gcnt, wcomb, bcomb, out);
}